// Round 9
// baseline (665.200 us; speedup 1.0000x reference)
//
#include <hip/hip_runtime.h>
#include <hip/hip_bf16.h>
#include <stdint.h>

// ---------------------------------------------------------------------------
// Self-attention, single head, d=1024, seq=2048, batch=4, fp32 in/out.
// R9: single persistent kernel with MANUAL grid barriers (R8's cooperative
//     launch silently failed -- unverifiable API). 1024 blocks, LDS 32 KB
//     (5/CU capacity), launch_bounds(256,4) caps VGPR at 128 (4/CU floor):
//     capacity 1280 >= 1024 so all blocks co-resident; HW fills any free
//     slot, no deadlock. Barriers: dedicated counter per boundary in the
//     last 256 B of d_out (zeroed by hipMemsetAsync each launch; only
//     overwritten by the final phase-3 tile after the last barrier).
//     Phase bodies identical to R7 (BK=64, XOR swizzle, 0 conflicts).
// Workspace (102 MiB): xb @ 0 (16; 1st MiB reused as part in phase 2+)
//   wcat @ 16 (6)  Q @ 22 (16)  K @ 38 (16)  Vt @ 54 (16)  S @ 70 (32)
// ---------------------------------------------------------------------------

typedef __attribute__((ext_vector_type(8))) short bf16x8;   // 8 bf16 = 4 VGPRs
typedef __attribute__((ext_vector_type(4))) float f32x4;

__device__ __forceinline__ void async_copy16(const void* g, void* l) {
  __builtin_amdgcn_global_load_lds(
      (__attribute__((address_space(1))) void*)(g),
      (__attribute__((address_space(3))) void*)(l),
      16, 0, 0);
}

// device-scope grid barrier: one counter per boundary, target = gridDim.x
__device__ __forceinline__ void grid_barrier(unsigned* cnt, unsigned target) {
  __syncthreads();
  if (threadIdx.x == 0) {
    __threadfence();                       // release prior writes device-wide
    atomicAdd(cnt, 1u);                    // device-scope by default (m20)
    while (__hip_atomic_load(cnt, __ATOMIC_RELAXED, __HIP_MEMORY_SCOPE_AGENT) < target)
      __builtin_amdgcn_s_sleep(32);
    __threadfence();                       // acquire
  }
  __syncthreads();
}

// ---------------- phase bodies (R7-verified) ----------------

__device__ __forceinline__ void phase_cast(
    const float* __restrict__ x,
    const float* __restrict__ Wq, const float* __restrict__ Wk,
    const float* __restrict__ Wv,
    __hip_bfloat16* __restrict__ xb, __hip_bfloat16* __restrict__ wcat)
{
  // x: 2097152 float4s, weights: 3 x 262144 float4s
  for (int i = blockIdx.x * 256 + threadIdx.x; i < 2883584; i += 1024 * 256) {
    const float* src;
    __hip_bfloat16* dst;
    int j;
    if (i < 2097152) {
      src = x; dst = xb; j = i;
    } else {
      const int k = i - 2097152;
      const int which = k >> 18;              // /262144
      src = (which == 0) ? Wq : (which == 1) ? Wk : Wv;
      dst = wcat + (long long)which * 1048576;
      j = k & 262143;
    }
    const float4 f = ((const float4*)src)[j];
    union { ushort4 u; __hip_bfloat16 h[4]; } r;
    r.h[0] = __float2bfloat16(f.x);
    r.h[1] = __float2bfloat16(f.y);
    r.h[2] = __float2bfloat16(f.z);
    r.h[3] = __float2bfloat16(f.w);
    ((ushort4*)dst)[j] = r.u;
  }
}

__device__ __forceinline__ void qkv_tile(
    char* smem,
    const __hip_bfloat16* __restrict__ A,
    const __hip_bfloat16* __restrict__ B,
    __hip_bfloat16* __restrict__ Q,
    __hip_bfloat16* __restrict__ Kk,
    __hip_bfloat16* __restrict__ Vt,
    int ty, int tx)
{
  __hip_bfloat16* As = (__hip_bfloat16*)smem;            // 128x64 = 16 KB
  __hip_bfloat16* Bs = (__hip_bfloat16*)(smem + 16384);  // 128x64 = 16 KB

  const int K = 1024;
  const long long tile_m = (long long)ty * 128;
  const long long tile_n = (long long)tx * 128;

  const int tid  = threadIdx.x;
  const int wid  = tid >> 6;
  const int lane = tid & 63;

  const int srow = wid * 8 + (lane >> 3);
  const int scol = (((lane & 7) ^ (lane >> 3))) * 8;     // XOR swizzle (R7)

  const __hip_bfloat16* aptr = A + (tile_m + srow) * K + scol;
  const __hip_bfloat16* bptr = B + (tile_n + srow) * K + scol;
  char* la = (char*)As + (wid * 8) * 128;
  char* lb = (char*)Bs + (wid * 8) * 128;

  const int wm   = (wid >> 1) * 64;
  const int wn   = (wid & 1) * 64;
  const int quad = lane >> 4;
  const int l16  = lane & 15;
  const int sw   = l16 & 7;

  const bf16x8* Asv = (const bf16x8*)As;
  const bf16x8* Bsv = (const bf16x8*)Bs;

  f32x4 acc[4][4];
  #pragma unroll
  for (int mi = 0; mi < 4; ++mi)
    #pragma unroll
    for (int ni = 0; ni < 4; ++ni)
      acc[mi][ni] = (f32x4){0.f, 0.f, 0.f, 0.f};

  for (int k0 = 0; k0 < K; k0 += 64) {
    #pragma unroll
    for (int p = 0; p < 4; ++p) {
      async_copy16(aptr + (long long)p * 32 * K, la + p * 32 * 128);
      async_copy16(bptr + (long long)p * 32 * K, lb + p * 32 * 128);
    }
    aptr += 64;
    bptr += 64;
    __syncthreads();

    #pragma unroll
    for (int kk = 0; kk < 2; ++kk) {
      bf16x8 af[4], bfr[4];
      const int ch = (kk * 4 + quad);
      #pragma unroll
      for (int mi = 0; mi < 4; ++mi) af[mi]  = Asv[(wm + mi * 16 + l16) * 8 + (ch ^ sw)];
      #pragma unroll
      for (int ni = 0; ni < 4; ++ni) bfr[ni] = Bsv[(wn + ni * 16 + l16) * 8 + (ch ^ sw)];
      #pragma unroll
      for (int mi = 0; mi < 4; ++mi)
        #pragma unroll
        for (int ni = 0; ni < 4; ++ni)
          acc[mi][ni] = __builtin_amdgcn_mfma_f32_16x16x32_bf16(af[mi], bfr[ni], acc[mi][ni], 0, 0, 0);
    }
    __syncthreads();
  }

  const int mat = (int)(tile_n >> 10);
  if (mat < 2) {
    // C/D layout (m89/m91): n = l16, m = quad*4 + r
    __hip_bfloat16* outp = (mat == 0) ? Q : Kk;
    const float scale = (mat == 0) ? 0.03125f : 1.0f;    // 1/sqrt(1024) in Q
    const int coln0 = (int)(tile_n & 1023);
    #pragma unroll
    for (int mi = 0; mi < 4; ++mi) {
      #pragma unroll
      for (int r = 0; r < 4; ++r) {
        const long long row = tile_m + wm + mi * 16 + quad * 4 + r;
        #pragma unroll
        for (int ni = 0; ni < 4; ++ni) {
          const int col = coln0 + wn + ni * 16 + l16;
          outp[row * 1024 + col] = __float2bfloat16(acc[mi][ni][r] * scale);
        }
      }
    }
  } else {
    // V: lane's 4 r-values are seq-consecutive -> one 8B store per (mi,ni).
    const int b    = (int)(tile_m >> 11);
    const int seq0 = (int)(tile_m & 2047);
    const int d0   = (int)(tile_n - 2048);
    #pragma unroll
    for (int mi = 0; mi < 4; ++mi) {
      const int seq = seq0 + wm + mi * 16 + quad * 4;
      #pragma unroll
      for (int ni = 0; ni < 4; ++ni) {
        const int d = d0 + wn + ni * 16 + l16;
        union { ushort4 u; unsigned short s[4]; } pk;
        #pragma unroll
        for (int r = 0; r < 4; ++r)
          pk.s[r] = __bfloat16_as_ushort(__float2bfloat16(acc[mi][ni][r]));
        *(ushort4*)(Vt + ((long long)(b * 1024 + d)) * 2048 + seq) = pk.u;
      }
    }
  }
}

__device__ __forceinline__ void s_exp_tile(
    char* smem,
    const __hip_bfloat16* __restrict__ Qg,
    const __hip_bfloat16* __restrict__ Kg,
    __hip_bfloat16* __restrict__ Sg,
    float* __restrict__ part,
    int bz, int ty, int tx)
{
  __hip_bfloat16* As = (__hip_bfloat16*)smem;
  __hip_bfloat16* Bs = (__hip_bfloat16*)(smem + 16384);

  const int K = 1024, N = 2048;
  const __hip_bfloat16* A = Qg + (long long)bz * 2048 * 1024;
  const __hip_bfloat16* B = Kg + (long long)bz * 2048 * 1024;

  const long long tile_m = (long long)ty * 128;
  const long long tile_n = (long long)tx * 128;

  const int tid  = threadIdx.x;
  const int wid  = tid >> 6;
  const int lane = tid & 63;

  const int srow = wid * 8 + (lane >> 3);
  const int scol = (((lane & 7) ^ (lane >> 3))) * 8;

  const __hip_bfloat16* aptr = A + (tile_m + srow) * K + scol;
  const __hip_bfloat16* bptr = B + (tile_n + srow) * K + scol;
  char* la = (char*)As + (wid * 8) * 128;
  char* lb = (char*)Bs + (wid * 8) * 128;

  const int wm   = (wid >> 1) * 64;
  const int wn   = (wid & 1) * 64;
  const int quad = lane >> 4;
  const int l16  = lane & 15;
  const int sw   = l16 & 7;

  const bf16x8* Asv = (const bf16x8*)As;
  const bf16x8* Bsv = (const bf16x8*)Bs;

  f32x4 acc[4][4];
  #pragma unroll
  for (int mi = 0; mi < 4; ++mi)
    #pragma unroll
    for (int ni = 0; ni < 4; ++ni)
      acc[mi][ni] = (f32x4){0.f, 0.f, 0.f, 0.f};

  for (int k0 = 0; k0 < K; k0 += 64) {
    #pragma unroll
    for (int p = 0; p < 4; ++p) {
      async_copy16(aptr + (long long)p * 32 * K, la + p * 32 * 128);
      async_copy16(bptr + (long long)p * 32 * K, lb + p * 32 * 128);
    }
    aptr += 64;
    bptr += 64;
    __syncthreads();

    #pragma unroll
    for (int kk = 0; kk < 2; ++kk) {
      bf16x8 af[4], bfr[4];
      const int ch = (kk * 4 + quad);
      #pragma unroll
      for (int mi = 0; mi < 4; ++mi) af[mi]  = Asv[(wm + mi * 16 + l16) * 8 + (ch ^ sw)];
      #pragma unroll
      for (int ni = 0; ni < 4; ++ni) bfr[ni] = Bsv[(wn + ni * 16 + l16) * 8 + (ch ^ sw)];
      #pragma unroll
      for (int mi = 0; mi < 4; ++mi)
        #pragma unroll
        for (int ni = 0; ni < 4; ++ni)
          acc[mi][ni] = __builtin_amdgcn_mfma_f32_16x16x32_bf16(af[mi], bfr[ni], acc[mi][ni], 0, 0, 0);
    }
    __syncthreads();
  }

  __hip_bfloat16* C = Sg + (long long)bz * 2048 * 2048;
  #pragma unroll
  for (int mi = 0; mi < 4; ++mi) {
    #pragma unroll
    for (int r = 0; r < 4; ++r) {
      const long long row = tile_m + wm + mi * 16 + quad * 4 + r;
      float s = 0.f;
      #pragma unroll
      for (int ni = 0; ni < 4; ++ni) {
        const float e = __expf(acc[mi][ni][r]);
        const __hip_bfloat16 h = __float2bfloat16(e);
        C[row * N + tile_n + wn + ni * 16 + l16] = h;
        s += __bfloat162float(h);
      }
      #pragma unroll
      for (int off = 1; off < 16; off <<= 1) s += __shfl_xor(s, off, 64);
      if (l16 == 0)
        part[((long long)bz * 2048 + row) * 32 + tx * 2 + (wid & 1)] = s;
    }
  }
}

__device__ __forceinline__ void pv_tile(
    char* smem,
    const __hip_bfloat16* __restrict__ Sg,
    const __hip_bfloat16* __restrict__ Vtg,
    const float* __restrict__ part,
    float* __restrict__ Cout,
    int bz, int ty, int tx)
{
  __hip_bfloat16* As = (__hip_bfloat16*)smem;            // 128x64 = 16 KB
  __hip_bfloat16* Bs = (__hip_bfloat16*)(smem + 16384);  // 64x64  =  8 KB
  float* rinv = (float*)(smem + 24576);                  // 128 floats

  const int K = 2048, N = 1024;
  const __hip_bfloat16* A = Sg  + (long long)bz * 2048 * 2048;
  const __hip_bfloat16* B = Vtg + (long long)bz * 1024 * 2048;

  const long long tile_m = (long long)ty * 128;
  const long long tile_n = (long long)tx * 64;

  const int tid  = threadIdx.x;
  const int wid  = tid >> 6;
  const int lane = tid & 63;

  const int srow = wid * 8 + (lane >> 3);
  const int scol = (((lane & 7) ^ (lane >> 3))) * 8;

  const __hip_bfloat16* aptr = A + (tile_m + srow) * K + scol;
  const __hip_bfloat16* bptr = B + (tile_n + srow) * K + scol;
  char* la = (char*)As + (wid * 8) * 128;
  char* lb = (char*)Bs + (wid * 8) * 128;

  const int wm   = (wid >> 1) * 64;
  const int wn   = (wid & 1) * 32;
  const int quad = lane >> 4;
  const int l16  = lane & 15;
  const int sw   = l16 & 7;

  const bf16x8* Asv = (const bf16x8*)As;
  const bf16x8* Bsv = (const bf16x8*)Bs;

  f32x4 acc[4][2];
  #pragma unroll
  for (int mi = 0; mi < 4; ++mi)
    #pragma unroll
    for (int ni = 0; ni < 2; ++ni)
      acc[mi][ni] = (f32x4){0.f, 0.f, 0.f, 0.f};

  for (int k0 = 0; k0 < K; k0 += 64) {
    #pragma unroll
    for (int p = 0; p < 4; ++p)
      async_copy16(aptr + (long long)p * 32 * K, la + p * 32 * 128);
    #pragma unroll
    for (int p = 0; p < 2; ++p)
      async_copy16(bptr + (long long)p * 32 * K, lb + p * 32 * 128);
    aptr += 64;
    bptr += 64;
    __syncthreads();

    #pragma unroll
    for (int kk = 0; kk < 2; ++kk) {
      bf16x8 af[4], bfr[2];
      const int ch = (kk * 4 + quad);
      #pragma unroll
      for (int mi = 0; mi < 4; ++mi) af[mi]  = Asv[(wm + mi * 16 + l16) * 8 + (ch ^ sw)];
      #pragma unroll
      for (int ni = 0; ni < 2; ++ni) bfr[ni] = Bsv[(wn + ni * 16 + l16) * 8 + (ch ^ sw)];
      #pragma unroll
      for (int mi = 0; mi < 4; ++mi)
        #pragma unroll
        for (int ni = 0; ni < 2; ++ni)
          acc[mi][ni] = __builtin_amdgcn_mfma_f32_16x16x32_bf16(af[mi], bfr[ni], acc[mi][ni], 0, 0, 0);
    }
    __syncthreads();
  }

  if (tid < 128) {
    const float4* pp = (const float4*)(part + ((long long)bz * 2048 + tile_m + tid) * 32);
    float s = 0.f;
    #pragma unroll
    for (int j = 0; j < 8; ++j) {
      const float4 f = pp[j];
      s += f.x + f.y + f.z + f.w;
    }
    rinv[tid] = 1.f / s;
  }
  __syncthreads();

  float* C = Cout + (long long)bz * 2048 * 1024;
  #pragma unroll
  for (int mi = 0; mi < 4; ++mi) {
    #pragma unroll
    for (int r = 0; r < 4; ++r) {
      const int rloc = wm + mi * 16 + quad * 4 + r;
      const float inv = rinv[rloc];
      const long long row = tile_m + rloc;
      #pragma unroll
      for (int ni = 0; ni < 2; ++ni) {
        const long long col = tile_n + wn + ni * 16 + l16;
        C[row * N + col] = acc[mi][ni][r] * inv;
      }
    }
  }
}

// ---------------- the persistent kernel (plain launch) ----------------
__global__ __launch_bounds__(256, 4)
void attn_all(const float* __restrict__ x,
              const float* __restrict__ Wq,
              const float* __restrict__ Wk,
              const float* __restrict__ Wv,
              float* __restrict__ out,
              char* __restrict__ ws,
              unsigned* __restrict__ bar)   // 3 counters, 64 B apart, zeroed
{
  __shared__ __align__(16) char smem[32768];

  __hip_bfloat16* xb   = (__hip_bfloat16*)(ws);
  float*          part = (float*)(ws);                   // reuses xb after qkv
  __hip_bfloat16* wcat = (__hip_bfloat16*)(ws + (16LL << 20));
  __hip_bfloat16* Q    = (__hip_bfloat16*)(ws + (22LL << 20));
  __hip_bfloat16* Kk   = (__hip_bfloat16*)(ws + (38LL << 20));
  __hip_bfloat16* Vt   = (__hip_bfloat16*)(ws + (54LL << 20));
  __hip_bfloat16* S    = (__hip_bfloat16*)(ws + (70LL << 20));

  // phase 0: casts
  phase_cast(x, Wq, Wk, Wv, xb, wcat);
  grid_barrier(bar + 0, 1024);

  // phase 1: QKV projection, 1536 tiles (24 x 64) over 1024 blocks
  for (int t = blockIdx.x; t < 1536; t += 1024) {
    const int tx = t % 24;
    const int ty = t / 24;
    qkv_tile(smem, xb, wcat, Q, Kk, Vt, ty, tx);
  }
  grid_barrier(bar + 16, 1024);

  // phase 2: S = exp(QK^T) + rowsum partials, 1024 tiles (16 x 16 x 4)
  {
    const int t  = blockIdx.x;
    const int tx = t & 15;
    const int ty = (t >> 4) & 15;
    const int bz = t >> 8;
    s_exp_tile(smem, Q, Kk, S, part, bz, ty, tx);
  }
  grid_barrier(bar + 32, 1024);

  // phase 3: O = (P Vt^T)/rowsum, 1024 tiles (16 x 16 x 4)
  {
    const int t  = blockIdx.x;
    const int tx = t & 15;
    const int ty = (t >> 4) & 15;
    const int bz = t >> 8;
    pv_tile(smem, S, Vt, part, out, bz, ty, tx);
  }
}

extern "C" void kernel_launch(void* const* d_in, const int* in_sizes, int n_in,
                              void* d_out, int out_size, void* d_ws, size_t ws_size,
                              hipStream_t stream)
{
  (void)in_sizes; (void)n_in; (void)ws_size;

  const float* x  = (const float*)d_in[0];
  const float* Wq = (const float*)d_in[1];
  const float* Wk = (const float*)d_in[2];
  const float* Wv = (const float*)d_in[3];
  float* out = (float*)d_out;
  char* ws = (char*)d_ws;

  // barrier counters: last 256 B of d_out (out_size = 8388608 floats).
  // Overwritten only by the final phase-3 tile, after the last barrier.
  unsigned* bar = (unsigned*)(out + out_size - 64);
  hipMemsetAsync(bar, 0, 256, stream);

  attn_all<<<dim3(1024), dim3(256), 0, stream>>>(x, Wq, Wk, Wv, out, ws, bar);
}